// Round 1
// 360.523 us; speedup vs baseline: 1.1508x; 1.1508x over previous
//
#include <hip/hip_runtime.h>
#include <hip/hip_bf16.h>

// Problem constants (fixed by reference): B=4, L=4096, R=8, DV=64
#define BB  4
#define LL  4096
#define RR  8
#define DVV 64

typedef __bf16 bf16x8 __attribute__((ext_vector_type(8)));
typedef float  f32x4  __attribute__((ext_vector_type(4)));

// ---------------------------------------------------------------------------
// Pre-kernel (256 blocks x 256 thr): v[b][m][d] fp32 -> vF fragment-linear
// bf16 MFMA B-fragments (unit = (b, colblk32, dblk16); lane l holds
// V[colblk*32 + (l>>4)*8 + j][dblk*16 + (l&15)], 16B contiguous per lane).
// ra2p/maskf staging from the previous version is gone: the main kernel now
// holds ra2 and mask in registers (one-time coalesced loads).
// ---------------------------------------------------------------------------
__global__ __launch_bounds__(256) void prep_kernel(
    const float* __restrict__ v, __bf16* __restrict__ vF) {
  __shared__ __bf16 tl[64][72];
  const int blk = blockIdx.x;         // 256 blocks
  const int b   = blk >> 6;           // 64 tiles per batch
  const int m0  = (blk & 63) << 6;
  const int tid = threadIdx.x;

  // load+transpose 64(m) x 64(d) tile to LDS [d][m]
  const float* vb = v + (((size_t)(b * LL + m0)) << 6);
#pragma unroll
  for (int i = 0; i < 16; ++i) {
    const int idx = (i << 8) + tid;   // m = idx>>6, d = idx&63
    tl[idx & 63][idx >> 6] = (__bf16)vb[idx];
  }
  __syncthreads();

  const int wv = tid >> 6, ln = tid & 63;
#pragma unroll
  for (int i = 0; i < 2; ++i) {
    const int u  = wv + (i << 2);
    const int cb = u >> 2, gg = u & 3;
    const int d  = gg * 16 + (ln & 15);
    const int c  = cb * 32 + ((ln >> 4) << 3);
    const size_t unit = ((size_t)(b * 128 + (m0 >> 5) + cb) << 2) + gg;
    *(bf16x8*)(vF + (unit << 9) + (ln << 3)) = *(const bf16x8*)&tl[d][c];
  }
}

// ---------------------------------------------------------------------------
// Main kernel: 1024 WGs x 512 thr (8 waves), 1 WG/CU (128.5 KB LDS).
// WG owns (b, 16 rows). Wave owns a 512-col chunk; lane owns 8 CONTIGUOUS
// columns (col0 = wave*512 + lane*8). ra2 (8r x 8cols) + mask live in
// registers for the whole kernel -> the score loop has ZERO vector loads.
// Scores are computed ONCE; e=exp(s)*mask staged to LDS as bf16
// (XOR-swizzled [16][512] per wave) and consumed twice:
//   (a) normalized fp32 attn store, lane-contiguous (2KB/row/wave),
//   (b) MFMA A-fragments for PV (normalization deferred to the epilogue).
// Epilogue barriers are lgkm-only (inline asm) so in-flight attn stores are
// NOT drained on the critical path.
// ---------------------------------------------------------------------------
__global__ __launch_bounds__(512, 2) void attn_main(
    const float* __restrict__ ra1, const float* __restrict__ ra2,
    const int* __restrict__ mask, const __bf16* __restrict__ vF,
    float* __restrict__ out, float* __restrict__ attn) {
  __shared__ __bf16 pbuf[8 * 16 * 512];   // 128 KB: [wave][row][col] bf16 e
  __shared__ float  red[8 * 16];          // per-wave partial row sums

  const int wg   = blockIdx.x;            // 0..1023
  const int b    = wg >> 8;               // 256 WGs per batch
  const int row0 = (wg & 255) << 4;       // 16 rows per WG
  const int tid  = threadIdx.x;
  const int wave = tid >> 6;              // 0..7
  const int lane = tid & 63;
  const int col0 = (wave << 9) + (lane << 3);

  // ---- one-time: ra2 chunk (8r x 8cols) + mask into registers ----
  const float* r2 = ra2 + (size_t)b * (RR * LL) + col0;
  f32x4 rlo[RR], rhi[RR];
#pragma unroll
  for (int r = 0; r < RR; ++r) {
    rlo[r] = *(const f32x4*)(r2 + r * LL);
    rhi[r] = *(const f32x4*)(r2 + r * LL + 4);
  }
  const int* mp = mask + (size_t)b * LL + col0;   // mask is [B][1][L]
  f32x4 mlo, mhi;
#pragma unroll
  for (int j = 0; j < 4; ++j) {
    mlo[j] = mp[j]     ? 1.0f : 0.0f;
    mhi[j] = mp[4 + j] ? 1.0f : 0.0f;
  }

  const float* a_base = ra1 + ((size_t)b * LL + row0) * RR;
  char* const  pw     = (char*)pbuf + (wave << 14);   // wave's 16 KB slice

  // ---- score phase: s -> e=exp(s)*mask, partial rsum, bf16 e -> LDS ----
#pragma unroll 2
  for (int i = 0; i < 16; ++i) {
    const float* ap = a_base + i * RR;   // row-uniform -> scalar loads
    f32x4 slo = {0.f, 0.f, 0.f, 0.f}, shi = {0.f, 0.f, 0.f, 0.f};
#pragma unroll
    for (int r = 0; r < RR; ++r) {
      const float a = ap[r];
#pragma unroll
      for (int j = 0; j < 4; ++j) {
        slo[j] = fmaf(a, rlo[r][j], slo[j]);
        shi[j] = fmaf(a, rhi[r][j], shi[j]);
      }
    }
    float e[8];
#pragma unroll
    for (int j = 0; j < 4; ++j) {
      e[j]     = __expf(slo[j]) * mlo[j];   // |s| <= ~17: exp safe in fp32
      e[4 + j] = __expf(shi[j]) * mhi[j];
    }
    float part = ((e[0] + e[1]) + (e[2] + e[3])) + ((e[4] + e[5]) + (e[6] + e[7]));
    part += __shfl_xor(part, 1);
    part += __shfl_xor(part, 2);
    part += __shfl_xor(part, 4);
    part += __shfl_xor(part, 8);
    part += __shfl_xor(part, 16);
    part += __shfl_xor(part, 32);
    if (lane == 0) red[wave * 16 + i] = part;

    bf16x8 pe;
#pragma unroll
    for (int j = 0; j < 8; ++j) pe[j] = (__bf16)e[j];
    // XOR swizzle of byte bits 4-6 with row: keeps writes/readbacks a pure
    // permutation (conflict-free) and spreads the MFMA A-frag reads to the
    // full-BW 8-accesses/bank minimum.
    *(bf16x8*)(pw + (i << 10) + ((lane << 4) ^ ((i & 7) << 4))) = pe;
  }
  __syncthreads();   // red[] complete (no global stores in flight yet)

  // ---- attn store: p = bf16(e) * rinv, lane-contiguous fp32 writes ----
  float* attn_base = attn + ((size_t)b * LL + row0) * LL + col0;
#pragma unroll 2
  for (int i = 0; i < 16; ++i) {
    float rt = 0.f;
#pragma unroll
    for (int w = 0; w < 8; ++w) rt += red[w * 16 + i];
    const float rinv = 1.0f / rt;
    const bf16x8 pe =
        *(const bf16x8*)(pw + (i << 10) + ((lane << 4) ^ ((i & 7) << 4)));
    f32x4 o0, o1;
#pragma unroll
    for (int j = 0; j < 4; ++j) {
      o0[j] = (float)pe[j] * rinv;
      o1[j] = (float)pe[4 + j] * rinv;
    }
    *(f32x4*)(attn_base + (size_t)i * LL)     = o0;
    *(f32x4*)(attn_base + (size_t)i * LL + 4) = o1;
  }

  // ---- PV MFMA over the wave's 512 cols (A = unnormalized bf16 e) ----
  const int lrow = lane & 15, kg = lane >> 4;
  f32x4 acc[4];
#pragma unroll
  for (int g = 0; g < 4; ++g) acc[g] = (f32x4){0.f, 0.f, 0.f, 0.f};
  const __bf16* vFb = vF + ((size_t)b << 18);
#pragma unroll 4
  for (int t = 0; t < 16; ++t) {
    const bf16x8 af = *(const bf16x8*)(
        pw + (lrow << 10) + (((t << 6) + (kg << 4)) ^ ((lrow & 7) << 4)));
    const __bf16* vblk = vFb + ((size_t)((wave << 4) + t) << 11) + (lane << 3);
#pragma unroll
    for (int g = 0; g < 4; ++g) {
      const bf16x8 bf = *(const bf16x8*)(vblk + (g << 9));
      acc[g] = __builtin_amdgcn_mfma_f32_16x16x32_bf16(af, bf, acc[g], 0, 0, 0);
    }
  }

  // ---- cross-wave O reduction: reuse pbuf; lgkm-only barriers so the
  //      in-flight attn stores are not drained here ----
  asm volatile("s_waitcnt lgkmcnt(0)\n\ts_barrier" ::: "memory");
  float* osum = (float*)pbuf;   // [8 waves][16 rows][64 d] fp32 = 32 KB
  // C/D layout: row = kg*4 + ii, col = g*16 + lrow
#pragma unroll
  for (int g = 0; g < 4; ++g)
#pragma unroll
    for (int ii = 0; ii < 4; ++ii)
      osum[(wave * 16 + kg * 4 + ii) * 64 + g * 16 + lrow] = acc[g][ii];
  asm volatile("s_waitcnt lgkmcnt(0)\n\ts_barrier" ::: "memory");

  if (tid < 256) {
    const int orow = tid >> 4;          // 0..15
    const int d    = (tid & 15) << 2;   // 0,4,..,60
    f32x4 o = {0.f, 0.f, 0.f, 0.f};
#pragma unroll
    for (int w = 0; w < 8; ++w) {
      const f32x4 rr = *(const f32x4*)(osum + ((w * 16 + orow) << 6) + d);
#pragma unroll
      for (int j = 0; j < 4; ++j) o[j] += rr[j];
    }
    float rt = 0.f;
#pragma unroll
    for (int w = 0; w < 8; ++w) rt += red[w * 16 + orow];
    const float rinv = 1.0f / rt;   // deferred normalization of PV
#pragma unroll
    for (int j = 0; j < 4; ++j) o[j] *= rinv;
    *(f32x4*)(out + ((size_t)b * LL + row0 + orow) * DVV + d) = o;
  }
}

extern "C" void kernel_launch(void* const* d_in, const int* in_sizes, int n_in,
                              void* d_out, int out_size, void* d_ws,
                              size_t ws_size, hipStream_t stream) {
  (void)in_sizes; (void)n_in; (void)out_size; (void)ws_size;
  const float* v    = (const float*)d_in[0];
  const int*   mask = (const int*)d_in[1];
  const float* ra1  = (const float*)d_in[2];
  const float* ra2  = (const float*)d_in[3];
  // d_in[4] = len_q, always 4096 (shapes fixed) -> constants above

  float* out  = (float*)d_out;
  float* attn = out + (size_t)BB * LL * DVV;   // outputs concatenated

  __bf16* vF = (__bf16*)d_ws;                  // 2 MB fragment-linear V

  hipLaunchKernelGGL(prep_kernel, dim3(BB * (LL / 64)), dim3(256), 0, stream,
                     v, vF);
  hipLaunchKernelGGL(attn_main, dim3(BB * LL / 16), dim3(512), 0, stream,
                     ra1, ra2, mask, vF, out, attn);
}

// Round 2
// 356.830 us; speedup vs baseline: 1.1627x; 1.0103x over previous
//
#include <hip/hip_runtime.h>
#include <hip/hip_bf16.h>

// Problem constants (fixed by reference): B=4, L=4096, R=8, DV=64
#define BB  4
#define LL  4096
#define RR  8
#define DVV 64

typedef __bf16 bf16x8 __attribute__((ext_vector_type(8)));
typedef float  f32x4  __attribute__((ext_vector_type(4)));

// ---------------------------------------------------------------------------
// Pre-kernel (256 blocks x 256 thr): v[b][m][d] fp32 -> vF fragment-linear
// bf16 MFMA B-fragments (unit = (b, colblk32, dblk16); lane l holds
// V[colblk*32 + (l>>4)*8 + j][dblk*16 + (l&15)], 16B contiguous per lane).
// ---------------------------------------------------------------------------
__global__ __launch_bounds__(256) void prep_kernel(
    const float* __restrict__ v, __bf16* __restrict__ vF) {
  __shared__ __bf16 tl[64][72];
  const int blk = blockIdx.x;         // 256 blocks
  const int b   = blk >> 6;           // 64 tiles per batch
  const int m0  = (blk & 63) << 6;
  const int tid = threadIdx.x;

  // load+transpose 64(m) x 64(d) tile to LDS [d][m]
  const float* vb = v + (((size_t)(b * LL + m0)) << 6);
#pragma unroll
  for (int i = 0; i < 16; ++i) {
    const int idx = (i << 8) + tid;   // m = idx>>6, d = idx&63
    tl[idx & 63][idx >> 6] = (__bf16)vb[idx];
  }
  __syncthreads();

  const int wv = tid >> 6, ln = tid & 63;
#pragma unroll
  for (int i = 0; i < 2; ++i) {
    const int u  = wv + (i << 2);
    const int cb = u >> 2, gg = u & 3;
    const int d  = gg * 16 + (ln & 15);
    const int c  = cb * 32 + ((ln >> 4) << 3);
    const size_t unit = ((size_t)(b * 128 + (m0 >> 5) + cb) << 2) + gg;
    *(bf16x8*)(vF + (unit << 9) + (ln << 3)) = *(const bf16x8*)&tl[d][c];
  }
}

// ---------------------------------------------------------------------------
// Main kernel: 2048 WGs x 512 thr (8 waves), 64 KB LDS -> 2 WGs/CU so one
// WG's attn-store drain overlaps the other's score/PV compute.
// WG owns (b, 8 rows). Wave owns a 512-col chunk; lane owns 8 CONTIGUOUS
// columns. ra2 (8r x 8cols) + mask live in registers for the whole kernel.
// Scores computed ONCE; e=exp(s)*mask staged to LDS bf16 (XOR-swizzled) and
// consumed twice: (a) normalized fp32 nontemporal attn store, (b) MFMA
// A-fragments for PV (normalization deferred to epilogue). A-fragment rows
// 8-15 are fed duplicates of rows 0-7 (MFMA C rows 8-15 = ignored copies).
// ---------------------------------------------------------------------------
__global__ __launch_bounds__(512, 4) void attn_main(
    const float* __restrict__ ra1, const float* __restrict__ ra2,
    const int* __restrict__ mask, const __bf16* __restrict__ vF,
    float* __restrict__ out, float* __restrict__ attn) {
  __shared__ __bf16 pbuf[8 * 8 * 512];    // 64 KB: [wave][row][col] bf16 e
  __shared__ float  red[8 * 8];           // per-wave partial row sums

  const int wg   = blockIdx.x;            // 0..2047
  const int b    = wg >> 9;               // 512 WGs per batch
  const int row0 = (wg & 511) << 3;       // 8 rows per WG
  const int tid  = threadIdx.x;
  const int wave = tid >> 6;              // 0..7
  const int lane = tid & 63;
  const int col0 = (wave << 9) + (lane << 3);

  // ---- one-time: ra2 chunk (8r x 8cols) + mask into registers ----
  const float* r2 = ra2 + (size_t)b * (RR * LL) + col0;
  f32x4 rlo[RR], rhi[RR];
#pragma unroll
  for (int r = 0; r < RR; ++r) {
    rlo[r] = *(const f32x4*)(r2 + r * LL);
    rhi[r] = *(const f32x4*)(r2 + r * LL + 4);
  }
  const int* mp = mask + (size_t)b * LL + col0;   // mask is [B][1][L]
  f32x4 mlo, mhi;
#pragma unroll
  for (int j = 0; j < 4; ++j) {
    mlo[j] = mp[j]     ? 1.0f : 0.0f;
    mhi[j] = mp[4 + j] ? 1.0f : 0.0f;
  }

  const float* a_base = ra1 + ((size_t)b * LL + row0) * RR;
  char* const  pw     = (char*)pbuf + (wave << 13);   // wave's 8 KB slice

  // ---- score phase: s -> e=exp(s)*mask, bf16 e -> LDS, per-row partials ----
  float part[8];
#pragma unroll
  for (int i = 0; i < 8; ++i) {
    const float* ap = a_base + i * RR;   // row-uniform -> scalar loads
    f32x4 slo = {0.f, 0.f, 0.f, 0.f}, shi = {0.f, 0.f, 0.f, 0.f};
#pragma unroll
    for (int r = 0; r < RR; ++r) {
      const float a = ap[r];
#pragma unroll
      for (int j = 0; j < 4; ++j) {
        slo[j] = fmaf(a, rlo[r][j], slo[j]);
        shi[j] = fmaf(a, rhi[r][j], shi[j]);
      }
    }
    float e[8];
#pragma unroll
    for (int j = 0; j < 4; ++j) {
      e[j]     = __expf(slo[j]) * mlo[j];   // |s| <= ~17: exp safe in fp32
      e[4 + j] = __expf(shi[j]) * mhi[j];
    }
    part[i] = ((e[0] + e[1]) + (e[2] + e[3])) + ((e[4] + e[5]) + (e[6] + e[7]));

    bf16x8 pe;
#pragma unroll
    for (int j = 0; j < 8; ++j) pe[j] = (__bf16)e[j];
    // XOR swizzle of byte bits 4-6 with row: pure permutation per row,
    // spreads MFMA A-frag readbacks across banks.
    *(bf16x8*)(pw + (i << 10) + ((lane << 4) ^ ((i & 7) << 4))) = pe;
  }
  // 8 independent butterfly chains, interleaved -> latency pipelined
#pragma unroll
  for (int s = 1; s < 64; s <<= 1)
#pragma unroll
    for (int i = 0; i < 8; ++i) part[i] += __shfl_xor(part[i], s);
  if (lane == 0) {
#pragma unroll
    for (int i = 0; i < 8; ++i) red[wave * 8 + i] = part[i];
  }
  __syncthreads();   // red[] complete (no global stores in flight yet)

  // ---- attn store: p = bf16(e) * rinv, lane-contiguous nontemporal ----
  float* attn_base = attn + ((size_t)b * LL + row0) * LL + col0;
#pragma unroll 2
  for (int i = 0; i < 8; ++i) {
    float rt = 0.f;
#pragma unroll
    for (int w = 0; w < 8; ++w) rt += red[w * 8 + i];
    const float rinv = 1.0f / rt;
    const bf16x8 pe =
        *(const bf16x8*)(pw + (i << 10) + ((lane << 4) ^ ((i & 7) << 4)));
    f32x4 o0, o1;
#pragma unroll
    for (int j = 0; j < 4; ++j) {
      o0[j] = (float)pe[j] * rinv;
      o1[j] = (float)pe[4 + j] * rinv;
    }
    __builtin_nontemporal_store(o0, (f32x4*)(attn_base + (size_t)i * LL));
    __builtin_nontemporal_store(o1, (f32x4*)(attn_base + (size_t)i * LL + 4));
  }

  // ---- PV MFMA over the wave's 512 cols (A = unnormalized bf16 e) ----
  const int lrow = lane & 15, kg = lane >> 4;
  const int lr8  = lrow & 7;              // A rows 8-15 duplicate rows 0-7
  f32x4 acc[4];
#pragma unroll
  for (int g = 0; g < 4; ++g) acc[g] = (f32x4){0.f, 0.f, 0.f, 0.f};
  const __bf16* vFb = vF + ((size_t)b << 18);
#pragma unroll 4
  for (int t = 0; t < 16; ++t) {
    const bf16x8 af = *(const bf16x8*)(
        pw + (lr8 << 10) + (((t << 6) + (kg << 4)) ^ (lr8 << 4)));
    const __bf16* vblk = vFb + ((size_t)((wave << 4) + t) << 11) + (lane << 3);
#pragma unroll
    for (int g = 0; g < 4; ++g) {
      const bf16x8 bf = *(const bf16x8*)(vblk + (g << 9));
      acc[g] = __builtin_amdgcn_mfma_f32_16x16x32_bf16(af, bf, acc[g], 0, 0, 0);
    }
  }

  // ---- cross-wave O reduction: reuse pbuf; lgkm-only barriers so in-flight
  //      attn stores are NOT drained here ----
  asm volatile("s_waitcnt lgkmcnt(0)\n\ts_barrier" ::: "memory");
  float* osum = (float*)pbuf;   // [8 waves][8 rows][64 d] fp32 = 16 KB
  // C/D layout: row = kg*4 + ii (valid rows 0-7 -> kg<2), col = g*16 + lrow
  if (kg < 2) {
#pragma unroll
    for (int g = 0; g < 4; ++g)
#pragma unroll
      for (int ii = 0; ii < 4; ++ii)
        osum[(wave * 8 + kg * 4 + ii) * 64 + g * 16 + lrow] = acc[g][ii];
  }
  asm volatile("s_waitcnt lgkmcnt(0)\n\ts_barrier" ::: "memory");

  if (tid < 128) {
    const int orow = tid >> 4;          // 0..7
    const int d    = (tid & 15) << 2;   // 0,4,..,60
    f32x4 o = {0.f, 0.f, 0.f, 0.f};
#pragma unroll
    for (int w = 0; w < 8; ++w) {
      const f32x4 rr = *(const f32x4*)(osum + ((w * 8 + orow) << 6) + d);
#pragma unroll
      for (int j = 0; j < 4; ++j) o[j] += rr[j];
    }
    float rt = 0.f;
#pragma unroll
    for (int w = 0; w < 8; ++w) rt += red[w * 8 + orow];
    const float rinv = 1.0f / rt;   // deferred normalization of PV
#pragma unroll
    for (int j = 0; j < 4; ++j) o[j] *= rinv;
    *(f32x4*)(out + ((size_t)b * LL + row0 + orow) * DVV + d) = o;
  }
}

extern "C" void kernel_launch(void* const* d_in, const int* in_sizes, int n_in,
                              void* d_out, int out_size, void* d_ws,
                              size_t ws_size, hipStream_t stream) {
  (void)in_sizes; (void)n_in; (void)out_size; (void)ws_size;
  const float* v    = (const float*)d_in[0];
  const int*   mask = (const int*)d_in[1];
  const float* ra1  = (const float*)d_in[2];
  const float* ra2  = (const float*)d_in[3];
  // d_in[4] = len_q, always 4096 (shapes fixed) -> constants above

  float* out  = (float*)d_out;
  float* attn = out + (size_t)BB * LL * DVV;   // outputs concatenated

  __bf16* vF = (__bf16*)d_ws;                  // 2 MB fragment-linear V

  hipLaunchKernelGGL(prep_kernel, dim3(BB * (LL / 64)), dim3(256), 0, stream,
                     v, vF);
  hipLaunchKernelGGL(attn_main, dim3(BB * LL / 8), dim3(512), 0, stream,
                     ra1, ra2, mask, vF, out, attn);
}

// Round 3
// 316.547 us; speedup vs baseline: 1.3107x; 1.1273x over previous
//
#include <hip/hip_runtime.h>
#include <hip/hip_bf16.h>

// Problem constants (fixed by reference): B=4, L=4096, R=8, DV=64
#define BB  4
#define LL  4096
#define RR  8
#define DVV 64

typedef __bf16 bf16x8 __attribute__((ext_vector_type(8)));
typedef __bf16 bf16x4 __attribute__((ext_vector_type(4)));
typedef float  f32x4  __attribute__((ext_vector_type(4)));
typedef int    i32x4  __attribute__((ext_vector_type(4)));

// ---------------------------------------------------------------------------
// Pre-kernel (256 blocks x 256 thr): v[b][m][d] fp32 -> vF fragment-linear
// bf16 MFMA B-fragments (unit = (b, colblk32, dblk16); lane l holds
// V[colblk*32 + (l>>4)*8 + j][dblk*16 + (l&15)], 16B contiguous per lane).
// ---------------------------------------------------------------------------
__global__ __launch_bounds__(256) void prep_kernel(
    const float* __restrict__ v, __bf16* __restrict__ vF) {
  __shared__ __bf16 tl[64][72];
  const int blk = blockIdx.x;         // 256 blocks
  const int b   = blk >> 6;           // 64 tiles per batch
  const int m0  = (blk & 63) << 6;
  const int tid = threadIdx.x;

  const float* vb = v + (((size_t)(b * LL + m0)) << 6);
#pragma unroll
  for (int i = 0; i < 16; ++i) {
    const int idx = (i << 8) + tid;   // m = idx>>6, d = idx&63
    tl[idx & 63][idx >> 6] = (__bf16)vb[idx];
  }
  __syncthreads();

  const int wv = tid >> 6, ln = tid & 63;
#pragma unroll
  for (int i = 0; i < 2; ++i) {
    const int u  = wv + (i << 2);
    const int cb = u >> 2, gg = u & 3;
    const int d  = gg * 16 + (ln & 15);
    const int c  = cb * 32 + ((ln >> 4) << 3);
    const size_t unit = ((size_t)(b * 128 + (m0 >> 5) + cb) << 2) + gg;
    *(bf16x8*)(vF + (unit << 9) + (ln << 3)) = *(const bf16x8*)&tl[d][c];
  }
}

// ---------------------------------------------------------------------------
// Main kernel: 2048 WGs x 512 thr (8 waves), 64.25 KB LDS -> 2 WGs/CU.
// WG owns (b, 8 rows). Wave owns 512 cols; lane owns cols {W+lane*4} and
// {W+256+lane*4} (two dense 256-col halves) so EVERY attn store instruction
// covers a fully-contiguous 1KB (whole 128B lines; previous layout wrote
// 16B-on/16B-off half-lines -> ~1.7 TB/s effective write BW, the measured
// plateau). Stores are trickled one-per-PV-step so write demand is smooth.
// ra2 (8r x 8cols) + mask live in registers; scores computed once;
// e=exp(s)*mask staged to LDS bf16 (XOR-swizzled), consumed as normalized
// fp32 attn (nontemporal) and as MFMA A-fragments (normalization deferred).
// ---------------------------------------------------------------------------
__global__ __launch_bounds__(512, 4) void attn_main(
    const float* __restrict__ ra1, const float* __restrict__ ra2,
    const int* __restrict__ mask, const __bf16* __restrict__ vF,
    float* __restrict__ out, float* __restrict__ attn) {
  __shared__ __bf16 pbuf[8 * 8 * 512];    // 64 KB: [wave][row][col] bf16 e
  __shared__ float  red[8][8];            // [row][wave] partial row sums

  const int wg   = blockIdx.x;            // 0..2047
  const int b    = wg >> 9;               // 512 WGs per batch
  const int row0 = (wg & 511) << 3;       // 8 rows per WG
  const int tid  = threadIdx.x;
  const int wave = tid >> 6;              // 0..7
  const int lane = tid & 63;
  const int W    = wave << 9;             // wave's 512-col chunk

  // ---- one-time: ra2 (8r x 2x4 cols) + mask into registers ----
  const float* r2 = ra2 + (size_t)b * (RR * LL) + W + (lane << 2);
  f32x4 rA[RR], rB[RR];
#pragma unroll
  for (int r = 0; r < RR; ++r) {
    rA[r] = *(const f32x4*)(r2 + r * LL);
    rB[r] = *(const f32x4*)(r2 + r * LL + 256);
  }
  const int* mp = mask + (size_t)b * LL + W + (lane << 2);   // mask [B][1][L]
  const i32x4 mAv = *(const i32x4*)mp;
  const i32x4 mBv = *(const i32x4*)(mp + 256);
  f32x4 mA, mB;
#pragma unroll
  for (int j = 0; j < 4; ++j) {
    mA[j] = mAv[j] ? 1.0f : 0.0f;
    mB[j] = mBv[j] ? 1.0f : 0.0f;
  }

  const float* a_base = ra1 + ((size_t)b * LL + row0) * RR;
  char* const  pw     = (char*)pbuf + (wave << 13);   // wave's 8 KB slice

  // ---- score phase: s -> e=exp(s)*mask, bf16 e -> LDS, per-row partials ----
  float part[8];
#pragma unroll
  for (int i = 0; i < 8; ++i) {
    const float* ap = a_base + i * RR;   // row-uniform -> scalar loads
    f32x4 sA = {0.f, 0.f, 0.f, 0.f}, sB = {0.f, 0.f, 0.f, 0.f};
#pragma unroll
    for (int r = 0; r < RR; ++r) {
      const float a = ap[r];
#pragma unroll
      for (int j = 0; j < 4; ++j) {
        sA[j] = fmaf(a, rA[r][j], sA[j]);
        sB[j] = fmaf(a, rB[r][j], sB[j]);
      }
    }
    f32x4 eA, eB;
#pragma unroll
    for (int j = 0; j < 4; ++j) {
      eA[j] = __expf(sA[j]) * mA[j];   // |s| <= ~17: exp safe in fp32
      eB[j] = __expf(sB[j]) * mB[j];
    }
    part[i] = ((eA[0] + eA[1]) + (eA[2] + eA[3])) +
              ((eB[0] + eB[1]) + (eB[2] + eB[3]));

    bf16x4 pA, pB;
#pragma unroll
    for (int j = 0; j < 4; ++j) { pA[j] = (__bf16)eA[j]; pB[j] = (__bf16)eB[j]; }
    // XOR swizzle (byte bits 4-6 ^ row): pure per-row permutation of 16B
    // blocks; keeps PV b128 readbacks bank-spread. b64 writes are 8B-aligned
    // within a 16B block -> swizzle-consistent with the b128 reads.
    const int swz = (i & 7) << 4;
    *(bf16x4*)(pw + (i << 10) + (((lane << 3)) ^ swz))       = pA;
    *(bf16x4*)(pw + (i << 10) + ((512 + (lane << 3)) ^ swz)) = pB;
  }
  // 8 independent butterfly chains, interleaved -> latency pipelined
#pragma unroll
  for (int s = 1; s < 64; s <<= 1)
#pragma unroll
    for (int i = 0; i < 8; ++i) part[i] += __shfl_xor(part[i], s);
  if (lane == 0) {
#pragma unroll
    for (int i = 0; i < 8; ++i) red[i][wave] = part[i];
  }
  __syncthreads();   // pbuf + red complete (no global stores in flight yet)

  // ---- per-row 1/rowsum (static-indexed so it stays in registers) ----
  float rinv[8];
#pragma unroll
  for (int i = 0; i < 8; ++i) {
    const f32x4 r0 = *(const f32x4*)&red[i][0];
    const f32x4 r1 = *(const f32x4*)&red[i][4];
    rinv[i] = 1.0f / (((r0[0] + r0[1]) + (r0[2] + r0[3])) +
                      ((r1[0] + r1[1]) + (r1[2] + r1[3])));
  }

  // ---- fused PV MFMA + trickled attn stores (fully unrolled) ----
  const int lrow = lane & 15, kg = lane >> 4;
  const int lr8  = lrow & 7;              // A rows 8-15 duplicate rows 0-7
  f32x4 acc[4];
#pragma unroll
  for (int g = 0; g < 4; ++g) acc[g] = (f32x4){0.f, 0.f, 0.f, 0.f};
  const __bf16* vFb = vF + ((size_t)b << 18);
  float* attn_base  = attn + ((size_t)b * LL + row0) * LL + W + (lane << 2);

#pragma unroll
  for (int i = 0; i < 8; ++i) {
#pragma unroll
    for (int h = 0; h < 2; ++h) {
      const int t = 2 * i + h;
      const bf16x8 af = *(const bf16x8*)(
          pw + (lr8 << 10) + (((t << 6) + (kg << 4)) ^ (lr8 << 4)));
      const __bf16* vblk =
          vFb + ((size_t)((wave << 4) + t) << 11) + (lane << 3);
#pragma unroll
      for (int g = 0; g < 4; ++g) {
        const bf16x8 bf = *(const bf16x8*)(vblk + (g << 9));
        acc[g] =
            __builtin_amdgcn_mfma_f32_16x16x32_bf16(af, bf, acc[g], 0, 0, 0);
      }
    }
    // one dense 1KB store per half, smooth write stream
    const int swz = (i & 7) << 4;
    const bf16x4 pA =
        *(const bf16x4*)(pw + (i << 10) + (((lane << 3)) ^ swz));
    const bf16x4 pB =
        *(const bf16x4*)(pw + (i << 10) + ((512 + (lane << 3)) ^ swz));
    f32x4 oA, oB;
#pragma unroll
    for (int j = 0; j < 4; ++j) {
      oA[j] = (float)pA[j] * rinv[i];
      oB[j] = (float)pB[j] * rinv[i];
    }
    __builtin_nontemporal_store(oA, (f32x4*)(attn_base + (size_t)i * LL));
    __builtin_nontemporal_store(oB, (f32x4*)(attn_base + (size_t)i * LL + 256));
  }

  // ---- cross-wave O reduction: reuse pbuf; lgkm-only barriers so in-flight
  //      attn stores are NOT drained here ----
  asm volatile("s_waitcnt lgkmcnt(0)\n\ts_barrier" ::: "memory");
  float* osum = (float*)pbuf;   // [8 waves][8 rows][64 d] fp32 = 16 KB
  // C/D layout: row = kg*4 + ii (valid rows 0-7 -> kg<2), col = g*16 + lrow
  if (kg < 2) {
#pragma unroll
    for (int g = 0; g < 4; ++g)
#pragma unroll
      for (int ii = 0; ii < 4; ++ii)
        osum[(wave * 8 + kg * 4 + ii) * 64 + g * 16 + lrow] = acc[g][ii];
  }
  asm volatile("s_waitcnt lgkmcnt(0)\n\ts_barrier" ::: "memory");

  if (tid < 128) {
    const int orow = tid >> 4;          // 0..7
    const int d    = (tid & 15) << 2;   // 0,4,..,60
    f32x4 o = {0.f, 0.f, 0.f, 0.f};
#pragma unroll
    for (int w = 0; w < 8; ++w) {
      const f32x4 rr = *(const f32x4*)(osum + ((w * 8 + orow) << 6) + d);
#pragma unroll
      for (int j = 0; j < 4; ++j) o[j] += rr[j];
    }
    float rt = 0.f;
#pragma unroll
    for (int w = 0; w < 8; ++w) rt += red[orow][w];
    const float rinv_o = 1.0f / rt;   // deferred normalization of PV
#pragma unroll
    for (int j = 0; j < 4; ++j) o[j] *= rinv_o;
    *(f32x4*)(out + ((size_t)b * LL + row0 + orow) * DVV + d) = o;
  }
}

extern "C" void kernel_launch(void* const* d_in, const int* in_sizes, int n_in,
                              void* d_out, int out_size, void* d_ws,
                              size_t ws_size, hipStream_t stream) {
  (void)in_sizes; (void)n_in; (void)out_size; (void)ws_size;
  const float* v    = (const float*)d_in[0];
  const int*   mask = (const int*)d_in[1];
  const float* ra1  = (const float*)d_in[2];
  const float* ra2  = (const float*)d_in[3];
  // d_in[4] = len_q, always 4096 (shapes fixed) -> constants above

  float* out  = (float*)d_out;
  float* attn = out + (size_t)BB * LL * DVV;   // outputs concatenated

  __bf16* vF = (__bf16*)d_ws;                  // 2 MB fragment-linear V

  hipLaunchKernelGGL(prep_kernel, dim3(BB * (LL / 64)), dim3(256), 0, stream,
                     v, vF);
  hipLaunchKernelGGL(attn_main, dim3(BB * LL / 8), dim3(512), 0, stream,
                     ra1, ra2, mask, vF, out, attn);
}